// Round 1
// baseline (922.255 us; speedup 1.0000x reference)
//
#include <hip/hip_runtime.h>

// Problem constants (QuantLinear: x[M,K] fp32, qweight[K,N/8] i32, qzeros[G,N/8] i32,
// scales[G,N] fp32, bias[N] fp32, groupsize=128) -> out[M,N] fp32
#define M_DIM 4096
#define N_DIM 12288
#define K_DIM 4096
#define NP    1536        // N/8 packed words per row
#define GS    128
// GEMM tiling: BM=BN=128, BK=64, 256 threads = 4 waves, wave tile 64x64 (4x4 of 16x16)

typedef unsigned short ushort_t;
typedef _Float16 half8 __attribute__((ext_vector_type(8)));
typedef unsigned short us8 __attribute__((ext_vector_type(8)));
typedef float f32x4 __attribute__((ext_vector_type(4)));

__device__ __forceinline__ unsigned short f2h(float f) {
  _Float16 h = (_Float16)f;
  return __builtin_bit_cast(unsigned short, h);
}

// async global->LDS, 16B per lane; LDS dst is wave-uniform base + lane*16
#define GLDS16(G, L) __builtin_amdgcn_global_load_lds(                      \
    (const __attribute__((address_space(1))) void*)(G),                     \
    (__attribute__((address_space(3))) void*)(L), 16, 0, 0)

// ---------------------------------------------------------------------------
// Dequant: qweight[K, N/8] + qzeros + scales -> Wt[N, K] f16 (B^T layout).
// One thread per 16B output chunk (8 k-values for one n). The 8 word loads per
// thread hit the same 1-2 cache lines per row-column; qweight is L3-resident.
__global__ __launch_bounds__(256) void dequant_wt_kernel(
    const int* __restrict__ qw, const int* __restrict__ qz,
    const float* __restrict__ sc, ushort_t* __restrict__ wt) {
  int cid = blockIdx.x * 256 + threadIdx.x;   // 0 .. N*(K/8)-1
  int n   = cid >> 9;                         // K/8 = 512 chunks per n-row
  int kc  = cid & 511;
  int k0  = kc << 3;
  int c   = n >> 3;                           // packed word column
  int j4  = (n & 7) * 4;                      // nibble shift
  int g   = k0 >> 7;                          // 8-k chunk never straddles a group
  int z   = (qz[g * NP + c] >> j4) & 0xF;
  float s = sc[g * N_DIM + n];
  us8 o;
#pragma unroll
  for (int i = 0; i < 8; ++i) {
    int q = (qw[(size_t)(k0 + i) * NP + c] >> j4) & 0xF;
    o[i] = f2h((float)(q - z) * s);
  }
  *(us8*)(wt + (size_t)n * K_DIM + k0) = o;   // coalesced 16B, 128B runs/8 lanes
}

// ---------------------------------------------------------------------------
// x fp32 -> f16, 8 elements/thread
__global__ __launch_bounds__(256) void cvt_x_kernel(
    const float* __restrict__ x, ushort_t* __restrict__ xb) {
  int cid = blockIdx.x * 256 + threadIdx.x;   // M*K/8 threads
  const float4* p = (const float4*)(x + (size_t)cid * 8);
  float4 a = p[0], b = p[1];
  us8 o;
  o[0] = f2h(a.x); o[1] = f2h(a.y); o[2] = f2h(a.z); o[3] = f2h(a.w);
  o[4] = f2h(b.x); o[5] = f2h(b.y); o[6] = f2h(b.z); o[7] = f2h(b.w);
  *(us8*)(xb + (size_t)cid * 8) = o;
}

// ---------------------------------------------------------------------------
// GEMM: C = X(f16)[M,K] * Wt(f16)[N,K]^T + bias. m97 structure: 128x128x64,
// global_load_lds staging, 16x16x32 f16 MFMA, XOR chunk swizzle in LDS.
// APRE: A from pre-converted f16 (glds) vs fp32 x with inline cvt.
// BPRE: B from pre-dequantized Wt (glds) vs inline dequant from qweight.
template <int APRE, int BPRE>
__global__ __launch_bounds__(256) void gemm_kernel(
    const ushort_t* __restrict__ Xb, const float* __restrict__ Xf,
    const ushort_t* __restrict__ Wt,
    const int* __restrict__ qw, const int* __restrict__ qz,
    const float* __restrict__ sc,
    const float* __restrict__ bias, float* __restrict__ out) {
  __shared__ __align__(16) ushort_t lsA[128 * 64];
  __shared__ __align__(16) ushort_t lsB[128 * 64];
  const int tid  = threadIdx.x;
  const int lane = tid & 63;
  const int wid  = tid >> 6;
  const int wm   = wid & 1;        // wave row (m) 0..1
  const int wn   = wid >> 1;       // wave col (n) 0..1
  const int m0   = blockIdx.y * 128;
  const int n0   = blockIdx.x * 128;

  f32x4 acc[4][4] = {};

  for (int kt = 0; kt < K_DIM / 64; ++kt) {
    const int kb = kt * 64;
    // ---- stage A tile [128 m][64 k], row-major, 16B chunk c stored at slot c^(r&7)
    if constexpr (APRE) {
#pragma unroll
      for (int i = 0; i < 4; ++i) {
        int cid = i * 256 + tid;
        int r = cid >> 3, scol = cid & 7;
        int c = scol ^ (r & 7);
        GLDS16(Xb + (size_t)(m0 + r) * K_DIM + kb + c * 8, lsA + cid * 8);
      }
    } else {
#pragma unroll
      for (int i = 0; i < 4; ++i) {
        int cid = i * 256 + tid;
        int r = cid >> 3, scol = cid & 7;
        int c = scol ^ (r & 7);
        const float* src = Xf + (size_t)(m0 + r) * K_DIM + kb + c * 8;
        float4 a = *(const float4*)src;
        float4 b = *(const float4*)(src + 4);
        us8 o;
        o[0] = f2h(a.x); o[1] = f2h(a.y); o[2] = f2h(a.z); o[3] = f2h(a.w);
        o[4] = f2h(b.x); o[5] = f2h(b.y); o[6] = f2h(b.z); o[7] = f2h(b.w);
        *(us8*)(lsA + cid * 8) = o;
      }
    }
    // ---- stage B tile [128 n][64 k]
    if constexpr (BPRE) {
#pragma unroll
      for (int i = 0; i < 4; ++i) {
        int cid = i * 256 + tid;
        int r = cid >> 3, scol = cid & 7;
        int c = scol ^ (r & 7);
        GLDS16(Wt + (size_t)(n0 + r) * K_DIM + kb + c * 8, lsB + cid * 8);
      }
    } else {
      // fused dequant fallback: 1024 packed words per tile, 4 per thread
#pragma unroll
      for (int i = 0; i < 4; ++i) {
        int wi = i * 256 + tid;          // 64 k-rows x 16 words
        int kl = wi >> 4, cw = wi & 15;
        int k = kb + kl;
        int g = k >> 7;
        int qword = qw[(size_t)k * NP + (n0 >> 3) + cw];
        int zword = qz[g * NP + (n0 >> 3) + cw];
        float4 s0 = *(const float4*)(sc + (size_t)g * N_DIM + n0 + cw * 8);
        float4 s1 = *(const float4*)(sc + (size_t)g * N_DIM + n0 + cw * 8 + 4);
        float sv[8] = {s0.x, s0.y, s0.z, s0.w, s1.x, s1.y, s1.z, s1.w};
#pragma unroll
        for (int j = 0; j < 8; ++j) {
          int nl = cw * 8 + j;
          int q = (qword >> (4 * j)) & 0xF;
          int z = (zword >> (4 * j)) & 0xF;
          lsB[nl * 64 + (((kl >> 3) ^ (nl & 7)) << 3) + (kl & 7)] =
              f2h((float)(q - z) * sv[j]);
        }
      }
    }
    __syncthreads();   // drains vmcnt(0): glds data visible in LDS
    // ---- compute: 2 k-steps of 32, 16 MFMA each
#pragma unroll
    for (int ks = 0; ks < 2; ++ks) {
      half8 af[4], bfr[4];
#pragma unroll
      for (int i = 0; i < 4; ++i) {
        int row = wm * 64 + i * 16 + (lane & 15);
        int c = ks * 4 + (lane >> 4);
        af[i] = *(const half8*)(lsA + (row * 8 + (c ^ (row & 7))) * 8);
      }
#pragma unroll
      for (int jj = 0; jj < 4; ++jj) {
        int row = wn * 64 + jj * 16 + (lane & 15);
        int c = ks * 4 + (lane >> 4);
        bfr[jj] = *(const half8*)(lsB + (row * 8 + (c ^ (row & 7))) * 8);
      }
#pragma unroll
      for (int i = 0; i < 4; ++i)
#pragma unroll
        for (int jj = 0; jj < 4; ++jj)
          acc[i][jj] = __builtin_amdgcn_mfma_f32_16x16x32_f16(
              af[i], bfr[jj], acc[i][jj], 0, 0, 0);
    }
    __syncthreads();   // frags consumed before next stage overwrites LDS
  }

  // ---- epilogue: C/D layout col=lane&15 (n), row=(lane>>4)*4+r (m)  [m89/m91]
#pragma unroll
  for (int jj = 0; jj < 4; ++jj) {
    int n = n0 + wn * 64 + jj * 16 + (lane & 15);
    float bv = bias[n];
#pragma unroll
    for (int i = 0; i < 4; ++i) {
      int mr = m0 + wm * 64 + i * 16 + ((lane >> 4) << 2);
#pragma unroll
      for (int r = 0; r < 4; ++r)
        out[(size_t)(mr + r) * N_DIM + n] = acc[i][jj][r] + bv;
    }
  }
}

// ---------------------------------------------------------------------------
extern "C" void kernel_launch(void* const* d_in, const int* in_sizes, int n_in,
                              void* d_out, int out_size, void* d_ws, size_t ws_size,
                              hipStream_t stream) {
  const float* x    = (const float*)d_in[0];
  const int*   qw   = (const int*)d_in[1];
  const int*   qz   = (const int*)d_in[2];
  const float* sc   = (const float*)d_in[3];
  const float* bias = (const float*)d_in[4];
  float*       out  = (float*)d_out;
  // d_in[5] = groupsize (=128, hardcoded)

  const size_t WT_BYTES = (size_t)N_DIM * K_DIM * 2;  // 96 MiB
  const size_t XB_BYTES = (size_t)M_DIM * K_DIM * 2;  // 32 MiB
  ushort_t* Wt = (ushort_t*)d_ws;
  ushort_t* Xb = (ushort_t*)((char*)d_ws + WT_BYTES);
  const bool hasWt = ws_size >= WT_BYTES;
  const bool hasXb = ws_size >= WT_BYTES + XB_BYTES;

  if (hasWt)
    dequant_wt_kernel<<<N_DIM * (K_DIM / 8) / 256, 256, 0, stream>>>(qw, qz, sc, Wt);
  if (hasXb)
    cvt_x_kernel<<<M_DIM * K_DIM / 8 / 256, 256, 0, stream>>>(x, Xb);

  dim3 grid(N_DIM / 128, M_DIM / 128);  // (96, 32)
  if (hasXb)
    gemm_kernel<1, 1><<<grid, 256, 0, stream>>>(Xb, x, Wt, qw, qz, sc, bias, out);
  else if (hasWt)
    gemm_kernel<0, 1><<<grid, 256, 0, stream>>>(nullptr, x, Wt, qw, qz, sc, bias, out);
  else
    gemm_kernel<0, 0><<<grid, 256, 0, stream>>>(nullptr, x, nullptr, qw, qz, sc, bias, out);
}

// Round 2
// 765.885 us; speedup vs baseline: 1.2042x; 1.2042x over previous
//
#include <hip/hip_runtime.h>

// Problem constants (QuantLinear: x[M,K] fp32, qweight[K,N/8] i32, qzeros[G,N/8] i32,
// scales[G,N] fp32, bias[N] fp32, groupsize=128) -> out[M,N] fp32
#define M_DIM 4096
#define N_DIM 12288
#define K_DIM 4096
#define NP    1536        // N/8 packed words per row
#define GS    128
// GEMM tiling: BM=BN=128, BK=64, 256 threads = 4 waves, wave tile 64x64 (4x4 of 16x16)

typedef unsigned short ushort_t;
typedef _Float16 half8 __attribute__((ext_vector_type(8)));
typedef unsigned short us8 __attribute__((ext_vector_type(8)));
typedef float f32x4 __attribute__((ext_vector_type(4)));

__device__ __forceinline__ unsigned short f2h(float f) {
  _Float16 h = (_Float16)f;
  return __builtin_bit_cast(unsigned short, h);
}

// async global->LDS, 16B per lane; LDS dst is wave-uniform base + lane*16
#define GLDS16(G, L) __builtin_amdgcn_global_load_lds(                      \
    (const __attribute__((address_space(1))) void*)(G),                     \
    (__attribute__((address_space(3))) void*)(L), 16, 0, 0)

// ---------------------------------------------------------------------------
// Dequant v2: LDS tile transpose. Block = 64 k x 128 n tile.
// Phase 1: stage 64x16 packed words coalesced (each qw word read exactly once
//   device-wide), XOR-swizzled so phase-2 reads are broadcast/2-way.
// Phase 2: thread = (n, k-half): 32 dequants, one contiguous 64B write run
//   (lane pairs form 128B runs). R1 version was transaction-bound: lane-adjacent
//   loads 48KB apart, 8 strided loads/thread -> ~350us. This is ~25us of traffic.
__global__ __launch_bounds__(256) void dequant_wt_kernel(
    const int* __restrict__ qw, const int* __restrict__ qz,
    const float* __restrict__ sc, ushort_t* __restrict__ wt) {
  __shared__ int ldsQ[64 * 16];
  __shared__ int ldsZ[16];
  const int tid = threadIdx.x;
  const int k0 = blockIdx.y * 64;
  const int n0 = blockIdx.x * 128;
  const int w0 = n0 >> 3;       // first packed word column of tile
  const int g  = k0 >> 7;       // 64-k tile lies inside one group (GS=128)
#pragma unroll
  for (int i = 0; i < 4; ++i) {
    int idx = i * 256 + tid;
    int row = idx >> 4, w = idx & 15;      // 16 words = 64B contiguous per row
    ldsQ[row * 16 + (w ^ (row & 15))] = qw[(size_t)(k0 + row) * NP + w0 + w];
  }
  if (tid < 16) ldsZ[tid] = qz[g * NP + w0 + tid];
  __syncthreads();
  const int nl  = tid >> 1;     // local n 0..127
  const int kh  = tid & 1;      // which 32-k half
  const int col = nl >> 3;
  const int j4  = (nl & 7) * 4;
  const int z   = (ldsZ[col] >> j4) & 0xF;
  const float s = sc[(size_t)g * N_DIM + n0 + nl];
  ushort_t* dst = wt + (size_t)(n0 + nl) * K_DIM + k0 + kh * 32;
#pragma unroll
  for (int c = 0; c < 4; ++c) {
    us8 o;
#pragma unroll
    for (int ii = 0; ii < 8; ++ii) {
      int row = kh * 32 + c * 8 + ii;
      int q = (ldsQ[row * 16 + (col ^ (row & 15))] >> j4) & 0xF;
      o[ii] = f2h((float)(q - z) * s);
    }
    *(us8*)(dst + c * 8) = o;
  }
}

// ---------------------------------------------------------------------------
// x fp32 -> f16, 8 elements/thread
__global__ __launch_bounds__(256) void cvt_x_kernel(
    const float* __restrict__ x, ushort_t* __restrict__ xb) {
  int cid = blockIdx.x * 256 + threadIdx.x;   // M*K/8 threads
  const float4* p = (const float4*)(x + (size_t)cid * 8);
  float4 a = p[0], b = p[1];
  us8 o;
  o[0] = f2h(a.x); o[1] = f2h(a.y); o[2] = f2h(a.z); o[3] = f2h(a.w);
  o[4] = f2h(b.x); o[5] = f2h(b.y); o[6] = f2h(b.z); o[7] = f2h(b.w);
  *(us8*)(xb + (size_t)cid * 8) = o;
}

// ---------------------------------------------------------------------------
// GEMM: C = X(f16)[M,K] * Wt(f16)[N,K]^T + bias. m97 structure: 128x128x64,
// global_load_lds staging, 16x16x32 f16 MFMA, XOR chunk swizzle in LDS.
// (unchanged from R1: 529us, 779 TF, MfmaUtil 35.3%, 0 bank conflicts)
template <int APRE, int BPRE>
__global__ __launch_bounds__(256) void gemm_kernel(
    const ushort_t* __restrict__ Xb, const float* __restrict__ Xf,
    const ushort_t* __restrict__ Wt,
    const int* __restrict__ qw, const int* __restrict__ qz,
    const float* __restrict__ sc,
    const float* __restrict__ bias, float* __restrict__ out) {
  __shared__ __align__(16) ushort_t lsA[128 * 64];
  __shared__ __align__(16) ushort_t lsB[128 * 64];
  const int tid  = threadIdx.x;
  const int lane = tid & 63;
  const int wid  = tid >> 6;
  const int wm   = wid & 1;        // wave row (m) 0..1
  const int wn   = wid >> 1;       // wave col (n) 0..1
  const int m0   = blockIdx.y * 128;
  const int n0   = blockIdx.x * 128;

  f32x4 acc[4][4] = {};

  for (int kt = 0; kt < K_DIM / 64; ++kt) {
    const int kb = kt * 64;
    // ---- stage A tile [128 m][64 k], row-major, 16B chunk c stored at slot c^(r&7)
    if constexpr (APRE) {
#pragma unroll
      for (int i = 0; i < 4; ++i) {
        int cid = i * 256 + tid;
        int r = cid >> 3, scol = cid & 7;
        int c = scol ^ (r & 7);
        GLDS16(Xb + (size_t)(m0 + r) * K_DIM + kb + c * 8, lsA + cid * 8);
      }
    } else {
#pragma unroll
      for (int i = 0; i < 4; ++i) {
        int cid = i * 256 + tid;
        int r = cid >> 3, scol = cid & 7;
        int c = scol ^ (r & 7);
        const float* src = Xf + (size_t)(m0 + r) * K_DIM + kb + c * 8;
        float4 a = *(const float4*)src;
        float4 b = *(const float4*)(src + 4);
        us8 o;
        o[0] = f2h(a.x); o[1] = f2h(a.y); o[2] = f2h(a.z); o[3] = f2h(a.w);
        o[4] = f2h(b.x); o[5] = f2h(b.y); o[6] = f2h(b.z); o[7] = f2h(b.w);
        *(us8*)(lsA + cid * 8) = o;
      }
    }
    // ---- stage B tile [128 n][64 k]
    if constexpr (BPRE) {
#pragma unroll
      for (int i = 0; i < 4; ++i) {
        int cid = i * 256 + tid;
        int r = cid >> 3, scol = cid & 7;
        int c = scol ^ (r & 7);
        GLDS16(Wt + (size_t)(n0 + r) * K_DIM + kb + c * 8, lsB + cid * 8);
      }
    } else {
      // fused dequant fallback: 1024 packed words per tile, 4 per thread
#pragma unroll
      for (int i = 0; i < 4; ++i) {
        int wi = i * 256 + tid;          // 64 k-rows x 16 words
        int kl = wi >> 4, cw = wi & 15;
        int k = kb + kl;
        int g = k >> 7;
        int qword = qw[(size_t)k * NP + (n0 >> 3) + cw];
        int zword = qz[g * NP + (n0 >> 3) + cw];
        float4 s0 = *(const float4*)(sc + (size_t)g * N_DIM + n0 + cw * 8);
        float4 s1 = *(const float4*)(sc + (size_t)g * N_DIM + n0 + cw * 8 + 4);
        float sv[8] = {s0.x, s0.y, s0.z, s0.w, s1.x, s1.y, s1.z, s1.w};
#pragma unroll
        for (int j = 0; j < 8; ++j) {
          int nl = cw * 8 + j;
          int q = (qword >> (4 * j)) & 0xF;
          int z = (zword >> (4 * j)) & 0xF;
          lsB[nl * 64 + (((kl >> 3) ^ (nl & 7)) << 3) + (kl & 7)] =
              f2h((float)(q - z) * sv[j]);
        }
      }
    }
    __syncthreads();   // drains vmcnt(0): glds data visible in LDS
    // ---- compute: 2 k-steps of 32, 16 MFMA each
#pragma unroll
    for (int ks = 0; ks < 2; ++ks) {
      half8 af[4], bfr[4];
#pragma unroll
      for (int i = 0; i < 4; ++i) {
        int row = wm * 64 + i * 16 + (lane & 15);
        int c = ks * 4 + (lane >> 4);
        af[i] = *(const half8*)(lsA + (row * 8 + (c ^ (row & 7))) * 8);
      }
#pragma unroll
      for (int jj = 0; jj < 4; ++jj) {
        int row = wn * 64 + jj * 16 + (lane & 15);
        int c = ks * 4 + (lane >> 4);
        bfr[jj] = *(const half8*)(lsB + (row * 8 + (c ^ (row & 7))) * 8);
      }
#pragma unroll
      for (int i = 0; i < 4; ++i)
#pragma unroll
        for (int jj = 0; jj < 4; ++jj)
          acc[i][jj] = __builtin_amdgcn_mfma_f32_16x16x32_f16(
              af[i], bfr[jj], acc[i][jj], 0, 0, 0);
    }
    __syncthreads();   // frags consumed before next stage overwrites LDS
  }

  // ---- epilogue: C/D layout col=lane&15 (n), row=(lane>>4)*4+r (m)  [m89/m91]
#pragma unroll
  for (int jj = 0; jj < 4; ++jj) {
    int n = n0 + wn * 64 + jj * 16 + (lane & 15);
    float bv = bias[n];
#pragma unroll
    for (int i = 0; i < 4; ++i) {
      int mr = m0 + wm * 64 + i * 16 + ((lane >> 4) << 2);
#pragma unroll
      for (int r = 0; r < 4; ++r)
        out[(size_t)(mr + r) * N_DIM + n] = acc[i][jj][r] + bv;
    }
  }
}

// ---------------------------------------------------------------------------
extern "C" void kernel_launch(void* const* d_in, const int* in_sizes, int n_in,
                              void* d_out, int out_size, void* d_ws, size_t ws_size,
                              hipStream_t stream) {
  const float* x    = (const float*)d_in[0];
  const int*   qw   = (const int*)d_in[1];
  const int*   qz   = (const int*)d_in[2];
  const float* sc   = (const float*)d_in[3];
  const float* bias = (const float*)d_in[4];
  float*       out  = (float*)d_out;
  // d_in[5] = groupsize (=128, hardcoded)

  const size_t WT_BYTES = (size_t)N_DIM * K_DIM * 2;  // 96 MiB
  const size_t XB_BYTES = (size_t)M_DIM * K_DIM * 2;  // 32 MiB
  ushort_t* Wt = (ushort_t*)d_ws;
  ushort_t* Xb = (ushort_t*)((char*)d_ws + WT_BYTES);
  const bool hasWt = ws_size >= WT_BYTES;
  const bool hasXb = ws_size >= WT_BYTES + XB_BYTES;

  if (hasWt) {
    dim3 dq_grid(N_DIM / 128, K_DIM / 64);  // (96, 64)
    dequant_wt_kernel<<<dq_grid, 256, 0, stream>>>(qw, qz, sc, Wt);
  }
  if (hasXb)
    cvt_x_kernel<<<M_DIM * K_DIM / 8 / 256, 256, 0, stream>>>(x, Xb);

  dim3 grid(N_DIM / 128, M_DIM / 128);  // (96, 32)
  if (hasXb)
    gemm_kernel<1, 1><<<grid, 256, 0, stream>>>(Xb, x, Wt, qw, qz, sc, bias, out);
  else if (hasWt)
    gemm_kernel<0, 1><<<grid, 256, 0, stream>>>(nullptr, x, Wt, qw, qz, sc, bias, out);
  else
    gemm_kernel<0, 0><<<grid, 256, 0, stream>>>(nullptr, x, nullptr, qw, qz, sc, bias, out);
}

// Round 3
// 691.795 us; speedup vs baseline: 1.3331x; 1.1071x over previous
//
#include <hip/hip_runtime.h>

// Problem constants (QuantLinear: x[M,K] fp32, qweight[K,N/8] i32, qzeros[G,N/8] i32,
// scales[G,N] fp32, bias[N] fp32, groupsize=128) -> out[M,N] fp32
#define M_DIM 4096
#define N_DIM 12288
#define K_DIM 4096
#define NP    1536        // N/8 packed words per row
#define GS    128
// GEMM tiling: BM=BN=128, BK=64, 256 threads = 4 waves, wave tile 64x64.
// R3: wave tile = 2x2 of 32x32x16 MFMA (was 4x4 of 16x16x32).

typedef unsigned short ushort_t;
typedef _Float16 half8 __attribute__((ext_vector_type(8)));
typedef unsigned short us8 __attribute__((ext_vector_type(8)));
typedef float f32x16 __attribute__((ext_vector_type(16)));

__device__ __forceinline__ unsigned short f2h(float f) {
  _Float16 h = (_Float16)f;
  return __builtin_bit_cast(unsigned short, h);
}

// async global->LDS, 16B per lane; LDS dst is wave-uniform base + lane*16
#define GLDS16(G, L) __builtin_amdgcn_global_load_lds(                      \
    (const __attribute__((address_space(1))) void*)(G),                     \
    (__attribute__((address_space(3))) void*)(L), 16, 0, 0)

#define DQ_BLOCKS (96 * 64)           // dequant: 96 n-tiles x 64 k-tiles
#define CVT_BLOCKS (M_DIM * K_DIM / 8 / 256)  // 8192

// ---------------------------------------------------------------------------
// Fused prep: blocks [0, DQ_BLOCKS) dequant qweight -> Wt[N,K] f16 (LDS tile
// transpose, R2 design: coalesced reads, 64B-run writes). Blocks after that
// convert x fp32 -> f16. One launch instead of two; tails overlap.
__global__ __launch_bounds__(256) void prep_kernel(
    const int* __restrict__ qw, const int* __restrict__ qz,
    const float* __restrict__ sc, ushort_t* __restrict__ wt,
    const float* __restrict__ x, ushort_t* __restrict__ xb) {
  __shared__ int ldsQ[64 * 16];
  __shared__ int ldsZ[16];
  const int tid = threadIdx.x;
  if (blockIdx.x >= DQ_BLOCKS) {
    // ---- x fp32 -> f16, 8 elements/thread
    int cid = (blockIdx.x - DQ_BLOCKS) * 256 + tid;
    const float4* p = (const float4*)(x + (size_t)cid * 8);
    float4 a = p[0], b = p[1];
    us8 o;
    o[0] = f2h(a.x); o[1] = f2h(a.y); o[2] = f2h(a.z); o[3] = f2h(a.w);
    o[4] = f2h(b.x); o[5] = f2h(b.y); o[6] = f2h(b.z); o[7] = f2h(b.w);
    *(us8*)(xb + (size_t)cid * 8) = o;
    return;
  }
  const int bx = blockIdx.x % 96;     // n-tile
  const int by = blockIdx.x / 96;     // k-tile
  const int k0 = by * 64;
  const int n0 = bx * 128;
  const int w0 = n0 >> 3;       // first packed word column of tile
  const int g  = k0 >> 7;       // 64-k tile lies inside one group (GS=128)
#pragma unroll
  for (int i = 0; i < 4; ++i) {
    int idx = i * 256 + tid;
    int row = idx >> 4, w = idx & 15;      // 16 words = 64B contiguous per row
    ldsQ[row * 16 + (w ^ (row & 15))] = qw[(size_t)(k0 + row) * NP + w0 + w];
  }
  if (tid < 16) ldsZ[tid] = qz[g * NP + w0 + tid];
  __syncthreads();
  const int nl  = tid >> 1;     // local n 0..127
  const int kh  = tid & 1;      // which 32-k half
  const int col = nl >> 3;
  const int j4  = (nl & 7) * 4;
  const int z   = (ldsZ[col] >> j4) & 0xF;
  const float s = sc[(size_t)g * N_DIM + n0 + nl];
  ushort_t* dst = wt + (size_t)(n0 + nl) * K_DIM + k0 + kh * 32;
#pragma unroll
  for (int c = 0; c < 4; ++c) {
    us8 o;
#pragma unroll
    for (int ii = 0; ii < 8; ++ii) {
      int row = kh * 32 + c * 8 + ii;
      int q = (ldsQ[row * 16 + (col ^ (row & 15))] >> j4) & 0xF;
      o[ii] = f2h((float)(q - z) * s);
    }
    *(us8*)(dst + c * 8) = o;
  }
}

// ---------------------------------------------------------------------------
// GEMM: C = X(f16)[M,K] * Wt(f16)[N,K]^T + bias. 128x128x64 block tile,
// global_load_lds staging, XOR chunk swizzle in LDS.
// R3 changes vs R2 (532us, 775 TF, MfmaUtil 35.8%):
//  - 32x32x16 f16 MFMA, 2x2 tiles/wave: 16 MFMA/k-tile @8cyc = 129cyc vs
//    32 @4.6 = 147cyc, half the issue slots. A/B frag: row=lane&31,
//    k=(lane>>5)*8+j. C/D: col=lane&31, row=(reg&3)+8*(reg>>2)+4*(lane>>5).
//  - grid swapped (m fastest): A (32 MiB) becomes the L3-resident operand,
//    B streams ~once. R2 FETCH was 650 MB vs 134 ideal (B refetched ~6x).
//  - nontemporal out stores: don't let 192 MiB of C evict A/B from L3.
template <int APRE, int BPRE>
__global__ __launch_bounds__(256) void gemm_kernel(
    const ushort_t* __restrict__ Xb, const float* __restrict__ Xf,
    const ushort_t* __restrict__ Wt,
    const int* __restrict__ qw, const int* __restrict__ qz,
    const float* __restrict__ sc,
    const float* __restrict__ bias, float* __restrict__ out) {
  __shared__ __align__(16) ushort_t lsA[128 * 64];
  __shared__ __align__(16) ushort_t lsB[128 * 64];
  const int tid  = threadIdx.x;
  const int lane = tid & 63;
  const int wid  = tid >> 6;
  const int wm   = wid & 1;        // wave row (m) 0..1
  const int wn   = wid >> 1;       // wave col (n) 0..1
  const int m0   = blockIdx.x * 128;   // m varies fastest across blocks
  const int n0   = blockIdx.y * 128;

  f32x16 acc[2][2] = {};

  for (int kt = 0; kt < K_DIM / 64; ++kt) {
    const int kb = kt * 64;
    // ---- stage A tile [128 m][64 k], row-major, 16B chunk c stored at slot c^(r&7)
    if constexpr (APRE) {
#pragma unroll
      for (int i = 0; i < 4; ++i) {
        int cid = i * 256 + tid;
        int r = cid >> 3, scol = cid & 7;
        int c = scol ^ (r & 7);
        GLDS16(Xb + (size_t)(m0 + r) * K_DIM + kb + c * 8, lsA + cid * 8);
      }
    } else {
#pragma unroll
      for (int i = 0; i < 4; ++i) {
        int cid = i * 256 + tid;
        int r = cid >> 3, scol = cid & 7;
        int c = scol ^ (r & 7);
        const float* src = Xf + (size_t)(m0 + r) * K_DIM + kb + c * 8;
        float4 a = *(const float4*)src;
        float4 b = *(const float4*)(src + 4);
        us8 o;
        o[0] = f2h(a.x); o[1] = f2h(a.y); o[2] = f2h(a.z); o[3] = f2h(a.w);
        o[4] = f2h(b.x); o[5] = f2h(b.y); o[6] = f2h(b.z); o[7] = f2h(b.w);
        *(us8*)(lsA + cid * 8) = o;
      }
    }
    // ---- stage B tile [128 n][64 k]
    if constexpr (BPRE) {
#pragma unroll
      for (int i = 0; i < 4; ++i) {
        int cid = i * 256 + tid;
        int r = cid >> 3, scol = cid & 7;
        int c = scol ^ (r & 7);
        GLDS16(Wt + (size_t)(n0 + r) * K_DIM + kb + c * 8, lsB + cid * 8);
      }
    } else {
      // fused dequant fallback: 1024 packed words per tile, 4 per thread
#pragma unroll
      for (int i = 0; i < 4; ++i) {
        int wi = i * 256 + tid;          // 64 k-rows x 16 words
        int kl = wi >> 4, cw = wi & 15;
        int k = kb + kl;
        int g = k >> 7;
        int qword = qw[(size_t)k * NP + (n0 >> 3) + cw];
        int zword = qz[g * NP + (n0 >> 3) + cw];
        float4 s0 = *(const float4*)(sc + (size_t)g * N_DIM + n0 + cw * 8);
        float4 s1 = *(const float4*)(sc + (size_t)g * N_DIM + n0 + cw * 8 + 4);
        float sv[8] = {s0.x, s0.y, s0.z, s0.w, s1.x, s1.y, s1.z, s1.w};
#pragma unroll
        for (int j = 0; j < 8; ++j) {
          int nl = cw * 8 + j;
          int q = (qword >> (4 * j)) & 0xF;
          int z = (zword >> (4 * j)) & 0xF;
          lsB[nl * 64 + (((kl >> 3) ^ (nl & 7)) << 3) + (kl & 7)] =
              f2h((float)(q - z) * sv[j]);
        }
      }
    }
    __syncthreads();   // drains vmcnt(0): glds data visible in LDS
    // ---- compute: 4 k-steps of 16, 4 MFMA (32x32x16) each
#pragma unroll
    for (int ks = 0; ks < 4; ++ks) {
      half8 af[2], bfr[2];
      const int h = lane >> 5;          // which 8-k run within the k-step
      const int c = ks * 2 + h;         // 16B chunk index 0..7
#pragma unroll
      for (int i = 0; i < 2; ++i) {
        int row = wm * 64 + i * 32 + (lane & 31);
        af[i] = *(const half8*)(lsA + (row * 8 + (c ^ (row & 7))) * 8);
      }
#pragma unroll
      for (int jj = 0; jj < 2; ++jj) {
        int row = wn * 64 + jj * 32 + (lane & 31);
        bfr[jj] = *(const half8*)(lsB + (row * 8 + (c ^ (row & 7))) * 8);
      }
#pragma unroll
      for (int i = 0; i < 2; ++i)
#pragma unroll
        for (int jj = 0; jj < 2; ++jj)
          acc[i][jj] = __builtin_amdgcn_mfma_f32_32x32x16_f16(
              af[i], bfr[jj], acc[i][jj], 0, 0, 0);
    }
    __syncthreads();   // frags consumed before next stage overwrites LDS
  }

  // ---- epilogue: 32x32 C/D layout col=lane&31, row=(reg&3)+8*(reg>>2)+4*(lane>>5)
  //      [m74/m101]. Nontemporal: C is never re-read; keep it out of L3.
#pragma unroll
  for (int jj = 0; jj < 2; ++jj) {
    int n = n0 + wn * 64 + jj * 32 + (lane & 31);
    float bv = bias[n];
#pragma unroll
    for (int i = 0; i < 2; ++i) {
      int mbase = m0 + wm * 64 + i * 32 + ((lane >> 5) << 2);
#pragma unroll
      for (int reg = 0; reg < 16; ++reg) {
        int m = mbase + (reg & 3) + ((reg >> 2) << 3);
        __builtin_nontemporal_store(acc[i][jj][reg] + bv,
                                    out + (size_t)m * N_DIM + n);
      }
    }
  }
}

// ---------------------------------------------------------------------------
extern "C" void kernel_launch(void* const* d_in, const int* in_sizes, int n_in,
                              void* d_out, int out_size, void* d_ws, size_t ws_size,
                              hipStream_t stream) {
  const float* x    = (const float*)d_in[0];
  const int*   qw   = (const int*)d_in[1];
  const int*   qz   = (const int*)d_in[2];
  const float* sc   = (const float*)d_in[3];
  const float* bias = (const float*)d_in[4];
  float*       out  = (float*)d_out;
  // d_in[5] = groupsize (=128, hardcoded)

  const size_t WT_BYTES = (size_t)N_DIM * K_DIM * 2;  // 96 MiB
  const size_t XB_BYTES = (size_t)M_DIM * K_DIM * 2;  // 32 MiB
  ushort_t* Wt = (ushort_t*)d_ws;
  ushort_t* Xb = (ushort_t*)((char*)d_ws + WT_BYTES);
  const bool hasWt = ws_size >= WT_BYTES;
  const bool hasXb = ws_size >= WT_BYTES + XB_BYTES;

  dim3 grid(M_DIM / 128, N_DIM / 128);  // (32, 96): m fastest for L3 locality
  if (hasXb) {
    prep_kernel<<<DQ_BLOCKS + CVT_BLOCKS, 256, 0, stream>>>(qw, qz, sc, Wt, x, Xb);
    gemm_kernel<1, 1><<<grid, 256, 0, stream>>>(Xb, x, Wt, qw, qz, sc, bias, out);
  } else if (hasWt) {
    prep_kernel<<<DQ_BLOCKS, 256, 0, stream>>>(qw, qz, sc, Wt, x, nullptr);
    gemm_kernel<0, 1><<<grid, 256, 0, stream>>>(nullptr, x, Wt, qw, qz, sc, bias, out);
  } else {
    gemm_kernel<0, 0><<<grid, 256, 0, stream>>>(nullptr, x, nullptr, qw, qz, sc, bias, out);
  }
}